// Round 4
// baseline (509.764 us; speedup 1.0000x reference)
//
#include <hip/hip_runtime.h>
#include <cstdint>
#include <cstddef>

#define NV 200000
#define NT 800000
#define ROWS 64
#define MBLK 3125   // 3125*64 = 200000 exactly
#define NBLK 3125   // 3125*256 = 800000 exactly (tet kernels)
#define NSEGS 196   // ceil(200000/1024) lo-segments
#define PCAP 4096   // pairs per segment arena (expected ~300; ~200 sigma margin)
#define AST 264     // A-tile row stride in halves
#define PST (ROWS*AST)

typedef unsigned int u32;
typedef unsigned long long u64;

typedef __attribute__((ext_vector_type(8))) _Float16 half8;
typedef __attribute__((ext_vector_type(4))) float f32x4;
typedef __attribute__((ext_vector_type(16))) float f32x16;
#define MFMA32F __builtin_amdgcn_mfma_f32_32x32x16_f16

// ---------------- marching-tets tables ----------------
__constant__ int c_tri[16][6] = {
  {-1,-1,-1,-1,-1,-1},{1,0,2,-1,-1,-1},{4,0,3,-1,-1,-1},{1,4,2,1,3,4},
  {3,1,5,-1,-1,-1},{2,3,0,2,5,3},{1,4,0,1,5,4},{4,2,5,-1,-1,-1},
  {4,5,2,-1,-1,-1},{4,1,0,4,5,1},{3,2,0,3,5,2},{1,3,5,-1,-1,-1},
  {4,1,2,4,3,1},{3,0,4,-1,-1,-1},{2,0,1,-1,-1,-1},{-1,-1,-1,-1,-1,-1}};
__constant__ int c_ntri[16] = {0,1,1,2,1,2,2,1,1,2,2,1,2,1,1,0};
__constant__ int c_be[12] = {0,1,0,2,0,3,1,2,1,3,2,3};

// ---------------- fp16 Dekker 2-way split: x ~= h + m*2^-11 ----------------
__device__ __forceinline__ void split2(float x, _Float16& h, _Float16& m){
  h = (_Float16)x;
  const float r = x - (float)h;
  m = (_Float16)(r * 2048.0f);
}

// ---------------- weight split prep (K-chunks of 16) + segment-cursor zeroing ----
// Layout per layer: wp[base + plane*PSZ + (c*256 + n)*16 + kk], c = k>>4, kk = k&15.
// Lane l of the MLP kernel loads 8 contiguous halves at n = l&31, kk = (l>>5)*8.
__global__ void split_weights(const float* __restrict__ w0, const float* __restrict__ w1,
                              const float* __restrict__ w2, const float* __restrict__ w3,
                              _Float16* __restrict__ wp, u32* __restrict__ segcur)
{
  const int t = blockIdx.x*256 + threadIdx.x;   // 0..25599 (100 blocks)
  if (t < 256) segcur[t] = 0u;
  int base, psz, c, kg, n, kvalid;
  const float* w;
  if (t < 1024){                                 // layer0: K=27 padded to 32 (2 chunks)
    base = 0; psz = 8192;
    c = t >> 9; kg = (t >> 8) & 1; n = t & 255;
    w = w0; kvalid = 27;
  } else {
    int r = t - 1024;
    const int l = r >> 13;                       // 0..2 -> layers 1..3 (16 chunks)
    r &= 8191;
    c = r >> 9; kg = (r >> 8) & 1; n = r & 255;
    base = 16384 + l*131072; psz = 65536;
    w = (l==0) ? w1 : (l==1) ? w2 : w3;
    kvalid = 256;
  }
  half8 hv, mv;
#pragma unroll
  for (int j=0;j<8;j++){
    const int k = c*16 + kg*8 + j;
    const float val = (k < kvalid) ? w[k*256 + n] : 0.f;
    _Float16 h, m; split2(val, h, m);
    hv[j] = h; mv[j] = m;
  }
  const int off = (c*256 + n)*16 + kg*8;
  *(half8*)(wp + base + off) = hv;
  *(half8*)(wp + base + psz + off) = mv;
}

// ---------------- MFMA MLP: 32x32x16 tiles, 32 rows x 64 cols per wave ----------
// Round-3 lesson: with A read from LDS directly inside compute(), all 6 MFMAs of a
// chunk depend on the 2 just-issued ds_read_b128 -> ~120cy exposed per chunk, 16x
// per layer (MfmaUtil 37). Fix: double-buffer the A fragments in REGISTERS one
// chunk ahead, symmetric with the B prefetch. compute() touches only registers;
// next chunk's ds_reads overlap the current chunk's MFMAs (~390cy of cover).
// Register budget: aA/aB 16 + bA/bB 32 + addr ~= 64 VGPR + 64 acc AGPR = 4-wave.
// Fragment conventions:
//   A: row = lane&31, k = (lane>>5)*8 + j   (8 contiguous halves -> ds_read_b128)
//   B: col = lane&31, k = (lane>>5)*8 + j   (contiguous in wp layout above)
//   C/D: col = lane&31, row = (reg&3) + 8*(reg>>2) + 4*(lane>>5)   [guide m74/m101]
template<int NCH, int PSZ, bool LAST>
__device__ __forceinline__ void layer_run(
    const _Float16* __restrict__ Wl, const float* __restrict__ Bv,
    const float* __restrict__ wfv,
    _Float16 (*Af)[ROWS][AST], float (*part)[5],
    int lane, int wv)
{
  const int l31 = lane & 31, hi = lane >> 5;
  const int rt = wv >> 2, cg = wv & 3;
  const int col0 = cg * 64;
  f32x16 g0[2], g1[2];
#pragma unroll
  for (int nt=0; nt<2; nt++){
#pragma unroll
    for (int r=0; r<16; r++){ g0[nt][r] = 0.f; g1[nt][r] = 0.f; }
  }

  const _Float16* bp = Wl + (u32)((col0 + l31)*16 + hi*8);
  const _Float16* ap0 = &Af[0][rt*32 + l31][hi*8];
  half8 bA[2][2], bB[2][2];            // [plane][nt]
  half8 aA[2], aB[2];                  // [plane]

  auto loadB = [&](int c, half8 (*dst)[2]){
#pragma unroll
    for (int p=0;p<2;p++)
#pragma unroll
      for (int nt=0;nt<2;nt++)
        dst[p][nt] = *(const half8*)(bp + p*PSZ + c*4096 + nt*512);
  };
  auto loadA = [&](int c, half8* dst){
    const _Float16* ap = ap0 + c*16;
    dst[0] = *(const half8*)(ap);
    dst[1] = *(const half8*)(ap + PST);
  };
  auto compute = [&](const half8* aa, const half8 (*bb)[2]){
#pragma unroll
    for (int nt=0;nt<2;nt++){
      g0[nt] = MFMA32F(aa[0], bb[0][nt], g0[nt], 0,0,0);   // h*h
      g1[nt] = MFMA32F(aa[0], bb[1][nt], g1[nt], 0,0,0);   // h*m'
      g1[nt] = MFMA32F(aa[1], bb[0][nt], g1[nt], 0,0,0);   // m'*h
    }
  };

  loadA(0, aA); loadB(0, bA);
#pragma unroll 1
  for (int ch=0; ch<NCH/2; ch++){
    const int c0 = 2*ch;
    loadA(c0+1, aB); loadB(c0+1, bB);
    compute(aA, bA);
    if (c0+2 < NCH){ loadA(c0+2, aA); loadB(c0+2, bA); }
    compute(aB, bB);
  }
  __syncthreads();

  const float S = 4.8828125e-4f;         // 2^-11
  if (!LAST){
#pragma unroll
    for (int nt=0;nt<2;nt++){
      const int col = col0 + nt*32 + l31;
      const float bias = Bv[col];
#pragma unroll
      for (int reg=0;reg<16;reg++){
        const int row = rt*32 + (reg&3) + 8*(reg>>2) + 4*hi;
        const float v = fmaxf(g0[nt][reg] + S*g1[nt][reg] + bias, 0.f);
        _Float16 h,m; split2(v,h,m);
        Af[0][row][col] = h; Af[1][row][col] = m;
      }
    }
  } else {
    float pr[16];
#pragma unroll
    for (int reg=0;reg<16;reg++) pr[reg] = 0.f;
#pragma unroll
    for (int nt=0;nt<2;nt++){
      const int col = col0 + nt*32 + l31;
      const float bias = Bv[col];
      const float w = wfv[col];
#pragma unroll
      for (int reg=0;reg<16;reg++)
        pr[reg] += fmaxf(g0[nt][reg] + S*g1[nt][reg] + bias, 0.f) * w;
    }
#pragma unroll
    for (int s=1;s<32;s<<=1)
#pragma unroll
      for (int reg=0;reg<16;reg++)
        pr[reg] += __shfl_xor(pr[reg], s, 64);
    if (l31 == 0){
#pragma unroll
      for (int reg=0;reg<16;reg++)
        part[rt*32 + (reg&3) + 8*(reg>>2) + 4*hi][cg] = pr[reg];
    }
  }
  __syncthreads();
}

__global__ __launch_bounds__(512,4) void mlp_mfma(
    const float* __restrict__ pos, const _Float16* __restrict__ wp,
    const float* __restrict__ b0, const float* __restrict__ b1,
    const float* __restrict__ b2, const float* __restrict__ b3,
    const float* __restrict__ wf, const float* __restrict__ bf,
    float* __restrict__ sdf)
{
  __shared__ _Float16 Af[2][ROWS][AST];    // 67,584 B
  __shared__ float part[ROWS][5];          // 1,280 B -> 68.9 KB = 2 blocks/CU
  const int tid = threadIdx.x;
  const int lane = tid & 63, wv = tid >> 6;
  const int row0 = blockIdx.x * ROWS;

#pragma unroll
  for (int it=0; it<4; it++){
    const int idx = it*512 + tid;          // 2048 = 64 rows x 32 k
    const int r = idx & 63, f = idx >> 6;
    float val = 0.f;
    if (f < 3){
      val = pos[(row0 + r)*3 + f];
    } else if (f < 27){
      const int g = (f-3)/6, rem = (f-3)%6;
      const int d = rem % 3;
      const float x = pos[(row0 + r)*3 + d];
      const float fr = (float)(1 << g) * 3.14159265358979323846f;
      val = (rem < 3) ? sinf(fr*x) : cosf(fr*x);
    }
    _Float16 h,m; split2(val,h,m);
    Af[0][r][f] = h; Af[1][r][f] = m;
  }
  __syncthreads();

  layer_run< 2,  8192,false>(wp + 0,      b0, nullptr, Af, part, lane, wv);
  layer_run<16, 65536,false>(wp + 16384,  b1, nullptr, Af, part, lane, wv);
  layer_run<16, 65536,false>(wp + 147456, b2, nullptr, Af, part, lane, wv);
  layer_run<16, 65536,true >(wp + 278528, b3, wf,      Af, part, lane, wv);

  if (tid < ROWS){
    float s = part[tid][0] + part[tid][1] + part[tid][2] + part[tid][3];
    sdf[row0 + tid] = s + bf[0];
  }
}

// ---------------- scan helpers ----------------
__device__ __forceinline__ u32 wave_scan_incl(u32 v, int lane){
#pragma unroll
  for (int s=1;s<64;s<<=1){
    const u32 y = __shfl_up(v, s, 64);
    if (lane >= s) v += y;
  }
  return v;
}
__device__ __forceinline__ u32 block_scan_fast(u32 v, u32* sh4, int tid){
  const int lane = tid & 63, wv = tid >> 6;
  const u32 incl = wave_scan_incl(v, lane);
  if (lane == 63) sh4[wv] = incl;
  __syncthreads();
  u32 base = 0;
#pragma unroll
  for (int w=0;w<3;w++) if (w < wv) base += sh4[w];
  return incl + base;
}
__device__ __forceinline__ u64 bscan_u64(u64 v, u64* sh, int tid){
  sh[tid]=v; __syncthreads();
#pragma unroll
  for (int s=1;s<256;s<<=1){
    const u64 y = (tid>=s) ? sh[tid-s] : 0ull;
    __syncthreads();
    sh[tid] += y;
    __syncthreads();
  }
  return sh[tid];
}

// ---------------- K1: codes, in-block stable (n1,n2) scan, pair append ----------------
__global__ void tet_pairs(const int* __restrict__ tet, const float* __restrict__ sdf,
    unsigned char* __restrict__ codes, u32* __restrict__ tscan, u32* __restrict__ tsum,
    u32* __restrict__ segcur, u64* __restrict__ pairs)
{
  __shared__ u32 sh4[4];
  const int tid = threadIdx.x;
  const int t = blockIdx.x*256 + tid;
  const int4 v = *(const int4*)(&tet[4*t]);
  const int o0 = sdf[v.x] > 0.f;
  const int o1 = sdf[v.y] > 0.f;
  const int o2 = sdf[v.z] > 0.f;
  const int o3 = sdf[v.w] > 0.f;
  const int code = o0 | (o1<<1) | (o2<<2) | (o3<<3);
  codes[t] = (unsigned char)code;
  const int nt = c_ntri[code];
  if (nt > 0){
    const int vv[4] = {v.x, v.y, v.z, v.w};
    const int oc[4] = {o0,o1,o2,o3};
#pragma unroll
    for (int e=0;e<6;e++){
      const int ia = c_be[2*e], ib = c_be[2*e+1];
      if (oc[ia] != oc[ib]){
        const int p = vv[ia], q = vv[ib];
        const int lo = p<q ? p : q, hi = p<q ? q : p;
        const int seg = lo >> 10;
        const u32 slot = atomicAdd(&segcur[seg], 1u);
        if (slot < PCAP)
          pairs[(size_t)seg*PCAP + slot] = ((u64)(u32)lo << 32) | (u32)hi;
      }
    }
  }
  const u32 my = (u32)(nt==1) | ((u32)(nt==2)<<16);
  const u32 incl = block_scan_fast(my, sh4, tid);
  tscan[t] = incl - my;
  if (tid == 255) tsum[blockIdx.x] = incl;
}

// ---------------- K2: per-segment sort+dedup+index (blocks 0..195); tsum scan (block 196)
__global__ void seg_process(const u64* __restrict__ pairs_in, const u32* __restrict__ segcur,
    u64* __restrict__ uq, u32* __restrict__ ucnt, u32* __restrict__ ucnt_ex,
    u32* __restrict__ usum, const u32* __restrict__ tsum, u64* __restrict__ tsumE,
    u32* __restrict__ meta)
{
  const int tid = threadIdx.x;
  if (blockIdx.x == NSEGS){
    // scan tsum[3125] (packed u16 pairs) -> tsumE u64 exclusive (n1 lo32, n2 hi32)
    __shared__ u64 sh64[256];
    u64 loc[13]; u64 tot = 0ull;
#pragma unroll
    for (int i=0;i<13;i++){
      const int idx = tid*13 + i;
      const u32 p = (idx < NBLK) ? tsum[idx] : 0u;
      const u64 u = (u64)(p & 0xffffu) | ((u64)(p >> 16) << 32);
      loc[i] = u; tot += u;
    }
    const u64 incl = bscan_u64(tot, sh64, tid);
    u64 run = incl - tot;
#pragma unroll
    for (int i=0;i<13;i++){
      const int idx = tid*13 + i;
      if (idx < NBLK) tsumE[idx] = run;
      run += loc[i];
    }
    if (tid == 255){ meta[0] = (u32)(incl & 0xffffffffull); meta[1] = (u32)(incl >> 32); }
    return;
  }

  __shared__ u64 P[PCAP];         // 32 KB
  __shared__ u32 sh4[4];
  __shared__ u32 shbase;
  const int seg = blockIdx.x;
  int n = (int)segcur[seg];
  if (n > PCAP) n = PCAP;
  int np = 1; while (np < n) np <<= 1;

  for (int i=tid; i<np; i+=256)
    P[i] = (i < n) ? pairs_in[(size_t)seg*PCAP + i] : ~0ull;
  if (tid == 0) shbase = 0u;
  __syncthreads();

  // bitonic sort P[0..np)
  for (int k=2; k<=np; k<<=1){
    for (int j=k>>1; j>0; j>>=1){
      for (int i=tid; i<np; i+=256){
        const int ij = i ^ j;
        if (ij > i){
          const u64 a = P[i], b = P[ij];
          const bool up = ((i & k) == 0);
          if ((a > b) == up){ P[i] = b; P[ij] = a; }
        }
      }
      __syncthreads();
    }
  }

  // dedup + in-place left compaction (chunked; dest <= src, reads precede writes)
  for (int c=0; c<n; c+=256){
    const int i = c + tid;
    u64 key = 0ull; u32 f = 0u;
    if (i < n){
      key = P[i];
      f = (i == 0 || P[i] != P[i-1]) ? 1u : 0u;
    }
    __syncthreads();
    const u32 incl = block_scan_fast(f, sh4, tid);
    const u32 base = shbase;
    if (f) P[base + incl - 1u] = key;
    __syncthreads();
    if (tid == 255) shbase = base + incl;
    __syncthreads();
  }
  const int uc = (int)shbase;

  // write compacted unique (lo,hi) keys to global arena (overwrites pairs region)
  for (int i=tid; i<uc; i+=256) uq[(size_t)seg*PCAP + i] = P[i];

  // per-lo counts and segment-relative exclusive offsets via binary search in LDS
  const int lo0 = seg << 10;
  for (int c=0; c<1024; c+=256){
    const int lo = lo0 + c + tid;
    if (lo < NV){
      const u64 kl = (u64)(u32)lo << 32;
      const u64 kh = (u64)(u32)(lo+1) << 32;
      int a=0, b=uc;
      while (a < b){ const int m=(a+b)>>1; if (P[m] < kl) a=m+1; else b=m; }
      const int lb = a;
      b = uc;
      while (a < b){ const int m=(a+b)>>1; if (P[m] < kh) a=m+1; else b=m; }
      ucnt_ex[lo] = (u32)lb;
      ucnt[lo] = (u32)(a - lb);
    }
  }
  if (tid == 0) usum[seg] = (u32)uc;
}

// ---------------- K3: emit verts (blocks 0..195) + faces (blocks 196..3320) ----------------
__global__ void emit_all(const int* __restrict__ tet, const float* __restrict__ pos,
    const float* __restrict__ sdf, const unsigned char* __restrict__ codes,
    const u32* __restrict__ tscan, const u64* __restrict__ tsumE, const u32* __restrict__ meta,
    const u64* __restrict__ uq, const u32* __restrict__ ucnt, const u32* __restrict__ ucnt_ex,
    const u32* __restrict__ usum, float* __restrict__ out, int out_size)
{
  __shared__ u32 sh4[4];
  __shared__ u32 shu[NSEGS];
  __shared__ u32 shM;
  const int tid = threadIdx.x;
  {
    const u32 v = (tid < NSEGS) ? usum[tid] : 0u;
    const u32 incl = block_scan_fast(v, sh4, tid);
    if (tid < NSEGS) shu[tid] = incl - v;
    if (tid == NSEGS-1) shM = incl;
    __syncthreads();
  }

  if (blockIdx.x < NSEGS){
    const int seg = blockIdx.x;
    const int uc = (int)usum[seg];
    const u32 base = shu[seg];
    for (int i=tid; i<uc; i+=256){
      const u64 key = uq[(size_t)seg*PCAP + i];
      const int lo = (int)(key >> 32);
      const int hi = (int)(key & 0xffffffffull);
      const float s0 = sdf[lo], s1 = sdf[hi];
      const float d = s0 - s1;
      const float vx = (pos[3*lo  ]*(-s1) + pos[3*hi  ]*s0) / d;
      const float vy = (pos[3*lo+1]*(-s1) + pos[3*hi+1]*s0) / d;
      const float vz = (pos[3*lo+2]*(-s1) + pos[3*hi+2]*s0) / d;
      const long long w = 3ll*(long long)(base + (u32)i);
      if (w + 3 <= (long long)out_size){
        out[w] = vx; out[w+1] = vy; out[w+2] = vz;
      }
    }
  } else {
    const int t = (blockIdx.x - NSEGS)*256 + tid;   // 3125 blocks -> t < 800000 exactly
    const int code = codes[t];
    const int nt = c_ntri[code];
    if (nt == 0) return;
    const u64 tb = tsumE[t>>8];
    const u32 ts = tscan[t];
    const u32 n1e = (u32)(tb & 0xffffffffull) + (ts & 0xffffu);
    const u32 n2e = (u32)(tb >> 32) + (ts >> 16);
    const u32 N1 = meta[0];
    const u32 M  = shM;
    const u32 fb = (nt==1) ? n1e : (N1 + 2u*n2e);
    const int4 v = *(const int4*)(&tet[4*t]);
    const int vv[4] = {v.x, v.y, v.z, v.w};
    for (int r=0;r<nt;r++){
      for (int k=0;k<3;k++){
        const int e = c_tri[code][3*r+k];
        const int ia = c_be[2*e], ib = c_be[2*e+1];
        const int p = vv[ia], q = vv[ib];
        const int lo = p<q ? p : q, hi = p<q ? q : p;
        const int seg = lo >> 10;
        const u32 st = ucnt_ex[lo];
        const int u = (int)ucnt[lo];
        const u64* b = uq + (size_t)seg*PCAP + st;
        int id = -1;
        for (int j=0;j<u;j++){
          if ((int)(b[j] & 0xffffffffull) == hi){ id = (int)(shu[seg] + st) + j; break; }
        }
        const long long w = 3ll*(long long)M + 3ll*(long long)(fb + (u32)r) + k;
        if (w < (long long)out_size && id >= 0) out[w] = (float)id;
      }
    }
  }
}

// ---------------- launch: 5 dispatches ----------------
extern "C" void kernel_launch(void* const* d_in, const int* in_sizes, int n_in,
                              void* d_out, int out_size, void* d_ws, size_t ws_size,
                              hipStream_t stream)
{
  (void)in_sizes; (void)n_in; (void)ws_size;
  const float* pos = (const float*)d_in[0];
  const int*   tet = (const int*)d_in[1];
  const float* w0 = (const float*)d_in[2];
  const float* b0 = (const float*)d_in[3];
  const float* w1 = (const float*)d_in[4];
  const float* b1 = (const float*)d_in[5];
  const float* w2 = (const float*)d_in[6];
  const float* b2 = (const float*)d_in[7];
  const float* w3 = (const float*)d_in[8];
  const float* b3 = (const float*)d_in[9];
  const float* wf = (const float*)d_in[10];
  const float* bf = (const float*)d_in[11];
  float* out = (float*)d_out;
  char* ws = (char*)d_ws;

  float*         sdf   = (float*)(ws + 0);               // 800000 B
  unsigned char* codes = (unsigned char*)(ws + 800000);  // 800000 B
  u32* tscan   = (u32*)(ws + 1600000);                   // 3200000 B
  u32* tsum    = (u32*)(ws + 4800000);                   // 12800 B (3125 used)
  u64* tsumE   = (u64*)(ws + 4812800);                   // 25088 B (3125 used)
  u32* segcur  = (u32*)(ws + 4837888);                   // 1024 B (196 used)
  u32* usum    = (u32*)(ws + 4838912);                   // 1024 B
  u32* meta    = (u32*)(ws + 4839936);                   // 64 B
  u32* ucnt    = (u32*)(ws + 4840000);                   // 800000 B
  u32* ucnt_ex = (u32*)(ws + 5640000);                   // 800000 B
  _Float16* wp = (_Float16*)(ws + 6440000);              // 819200 B
  u64* pairs   = (u64*)(ws + 7259200);                   // 196*4096*8 = 6422528 B (reused as uq)
  // total ws: 13,681,728 B (< 17.6 MB proven available in prior rounds)

  split_weights<<<100,256,0,stream>>>(w0,w1,w2,w3,wp,segcur);
  mlp_mfma<<<MBLK,512,0,stream>>>(pos,wp,b0,b1,b2,b3,wf,bf,sdf);

  tet_pairs<<<NBLK,256,0,stream>>>(tet,sdf,codes,tscan,tsum,segcur,pairs);
  seg_process<<<NSEGS+1,256,0,stream>>>(pairs,segcur,pairs,ucnt,ucnt_ex,usum,tsum,tsumE,meta);
  emit_all<<<NSEGS+NBLK,256,0,stream>>>(tet,pos,sdf,codes,tscan,tsumE,meta,
                                        pairs,ucnt,ucnt_ex,usum,out,out_size);
}

// Round 5
// 475.774 us; speedup vs baseline: 1.0714x; 1.0714x over previous
//
#include <hip/hip_runtime.h>
#include <cstdint>
#include <cstddef>

#define NV 200000
#define NT 800000
#define ROWS 128
#define MBLK 1563   // ceil(200000/128)
#define NBLK 3125   // 3125*256 = 800000 exactly (tet kernels)
#define NSEGS 196   // ceil(200000/1024) lo-segments
#define PCAP 4096   // pairs per segment arena (expected ~300; ~200 sigma margin)
#define AST 264     // A-tile row stride in halves
#define PST (ROWS*AST)

typedef unsigned int u32;
typedef unsigned long long u64;

typedef __attribute__((ext_vector_type(8))) _Float16 half8;
typedef __attribute__((ext_vector_type(4))) float f32x4;
#define MFMA16F __builtin_amdgcn_mfma_f32_16x16x32_f16

// ---------------- marching-tets tables ----------------
__constant__ int c_tri[16][6] = {
  {-1,-1,-1,-1,-1,-1},{1,0,2,-1,-1,-1},{4,0,3,-1,-1,-1},{1,4,2,1,3,4},
  {3,1,5,-1,-1,-1},{2,3,0,2,5,3},{1,4,0,1,5,4},{4,2,5,-1,-1,-1},
  {4,5,2,-1,-1,-1},{4,1,0,4,5,1},{3,2,0,3,5,2},{1,3,5,-1,-1,-1},
  {4,1,2,4,3,1},{3,0,4,-1,-1,-1},{2,0,1,-1,-1,-1},{-1,-1,-1,-1,-1,-1}};
__constant__ int c_ntri[16] = {0,1,1,2,1,2,2,1,1,2,2,1,2,1,1,0};
__constant__ int c_be[12] = {0,1,0,2,0,3,1,2,1,3,2,3};

// ---------------- fp16 Dekker 2-way split: x ~= h + m*2^-11 ----------------
__device__ __forceinline__ void split2(float x, _Float16& h, _Float16& m){
  h = (_Float16)x;
  const float r = x - (float)h;
  m = (_Float16)(r * 2048.0f);
}

// ---------------- weight split prep (K-chunks of 32, r2 layout) ----------------
// wp[base + plane*PSZ + (c*256 + n)*32 + kk], c = k>>5, kk = k&31.
__global__ void split_weights(const float* __restrict__ w0, const float* __restrict__ w1,
                              const float* __restrict__ w2, const float* __restrict__ w3,
                              _Float16* __restrict__ wp, u32* __restrict__ segcur)
{
  const int t = blockIdx.x*256 + threadIdx.x;   // 0..25599 (100 blocks)
  if (t < 256) segcur[t] = 0u;
  int base, psz, c, kg, n, kvalid;
  const float* w;
  if (t < 1024){                                 // layer0: K=27 padded to 32
    base = 0; psz = 8192; c = 0;
    kg = t >> 8; n = t & 255;
    w = w0; kvalid = 27;
  } else {
    int r = t - 1024;
    const int l = r >> 13;                       // 0..2 -> layers 1..3
    r &= 8191;
    c = r >> 10; kg = (r >> 8) & 3; n = r & 255;
    base = 16384 + l*131072; psz = 65536;
    w = (l==0) ? w1 : (l==1) ? w2 : w3;
    kvalid = 256;
  }
  half8 hv, mv;
#pragma unroll
  for (int j=0;j<8;j++){
    const int k = c*32 + kg*8 + j;
    const float val = (k < kvalid) ? w[k*256 + n] : 0.f;
    _Float16 h, m; split2(val, h, m);
    hv[j] = h; mv[j] = m;
  }
  const int off = (c*256 + n)*32 + kg*8;
  *(half8*)(wp + base + off) = hv;
  *(half8*)(wp + base + psz + off) = mv;
}

// ---------------- MFMA MLP: 64x64 wave tiles (RC=4096), ROWS=128/block ----------
// Cost model (verified against r2=253us and r3=313us): per output cell
//   MFMA 0.396 cy (invariant), A-LDS 12/C cy, B-L2 18.3/R cy.
// r2 was (R=64,C=32)=1.06 cy/cell. This kernel: (R=64,C=64)=0.87 cy/cell by
// doubling the per-wave accumulator tile (acc 64->128 regs). 8 waves cover
// 128 rows x 256 cols; in-place Af update between barriers as before.
// lb(512,2): 2 waves/SIMD, reg budget 256/wave (acc 128 + B dbuf 64 + ~30 addr).
template<int NC, int PSZ, bool LAST>
__device__ __forceinline__ void layer_run(
    const _Float16* __restrict__ Wl, const float* __restrict__ Bv,
    const float* __restrict__ wfv,
    _Float16 (*Af)[ROWS][AST], float (*part)[5],
    int lane, int wv)
{
  const int l15 = lane & 15, q = lane >> 4;
  const int rh = wv & 1, cs = wv >> 1;     // row half (64), col slab (64)
  const int row_base = rh * 64;
  const int col0 = cs * 64;
  f32x4 g0[4][4], g1[4][4];                // [mt][nt] -> 128 acc regs
#pragma unroll
  for (int i=0;i<4;i++)
#pragma unroll
    for (int j=0;j<4;j++){ g0[i][j] = (f32x4){0.f,0.f,0.f,0.f}; g1[i][j] = (f32x4){0.f,0.f,0.f,0.f}; }

  const _Float16* bp = Wl + (u32)((col0 + l15)*32 + q*8);
  half8 bA[2][4], bB[2][4];                // [plane][nt]

  auto loadB = [&](int c, half8 (*dst)[4]){
#pragma unroll
    for (int p=0;p<2;p++)
#pragma unroll
      for (int nt=0;nt<4;nt++)
        dst[p][nt] = *(const half8*)(bp + p*PSZ + c*8192 + nt*512);
  };
  auto compute = [&](int c, const half8 (*bb)[4]){
#pragma unroll
    for (int mt=0;mt<4;mt++){
      const _Float16* ap = &Af[0][row_base + mt*16 + l15][c*32 + q*8];
      const half8 ah = *(const half8*)(ap);
      const half8 am = *(const half8*)(ap + PST);
#pragma unroll
      for (int nt=0;nt<4;nt++){
        g0[mt][nt] = MFMA16F(ah, bb[0][nt], g0[mt][nt], 0,0,0);   // h*h
        g1[mt][nt] = MFMA16F(ah, bb[1][nt], g1[mt][nt], 0,0,0);   // h*m'
        g1[mt][nt] = MFMA16F(am, bb[0][nt], g1[mt][nt], 0,0,0);   // m'*h
      }
    }
  };

  loadB(0, bA);
  if (NC == 1){
    compute(0, bA);
  } else {
#pragma unroll 1
    for (int ch=0; ch<NC/2; ch++){
      const int c0 = 2*ch;
      loadB(c0+1, bB);
      compute(c0, bA);
      if (c0+2 < NC) loadB(c0+2, bA);
      compute(c0+1, bB);
    }
  }
  __syncthreads();

  const float S = 4.8828125e-4f;         // 2^-11
  if (!LAST){
#pragma unroll
    for (int nt=0;nt<4;nt++){
      const int col = col0 + nt*16 + l15;
      const float bias = Bv[col];
#pragma unroll
      for (int mt=0;mt<4;mt++)
#pragma unroll
        for (int reg=0;reg<4;reg++){
          const int row = row_base + mt*16 + q*4 + reg;
          const float v = fmaxf(g0[mt][nt][reg] + S*g1[mt][nt][reg] + bias, 0.f);
          _Float16 h,m; split2(v,h,m);
          Af[0][row][col] = h; Af[1][row][col] = m;
        }
    }
  } else {
    float pr[4][4];
#pragma unroll
    for (int mt=0;mt<4;mt++)
#pragma unroll
      for (int reg=0;reg<4;reg++) pr[mt][reg] = 0.f;
#pragma unroll
    for (int nt=0;nt<4;nt++){
      const int col = col0 + nt*16 + l15;
      const float bias = Bv[col];
      const float w = wfv[col];
#pragma unroll
      for (int mt=0;mt<4;mt++)
#pragma unroll
        for (int reg=0;reg<4;reg++)
          pr[mt][reg] += fmaxf(g0[mt][nt][reg] + S*g1[mt][nt][reg] + bias, 0.f) * w;
    }
#pragma unroll
    for (int s=1;s<16;s<<=1)
#pragma unroll
      for (int mt=0;mt<4;mt++)
#pragma unroll
        for (int reg=0;reg<4;reg++)
          pr[mt][reg] += __shfl_xor(pr[mt][reg], s, 64);
    if (l15 == 0){
#pragma unroll
      for (int mt=0;mt<4;mt++)
#pragma unroll
        for (int reg=0;reg<4;reg++)
          part[row_base + mt*16 + q*4 + reg][cs] = pr[mt][reg];
    }
  }
  __syncthreads();
}

__global__ __launch_bounds__(512,2) void mlp_mfma(
    const float* __restrict__ pos, const _Float16* __restrict__ wp,
    const float* __restrict__ b0, const float* __restrict__ b1,
    const float* __restrict__ b2, const float* __restrict__ b3,
    const float* __restrict__ wf, const float* __restrict__ bf,
    float* __restrict__ sdf)
{
  __shared__ _Float16 Af[2][ROWS][AST];    // 135,168 B
  __shared__ float part[ROWS][5];          // 2,560 B -> 137,728 B total (1 blk/CU, proven r1)
  const int tid = threadIdx.x;
  const int lane = tid & 63, wv = tid >> 6;
  const int row0 = blockIdx.x * ROWS;

#pragma unroll
  for (int it=0; it<8; it++){
    const int idx = it*512 + tid;          // 4096 = 128 rows x 32 k
    const int r = idx & 127, f = idx >> 7;
    const int gr = row0 + r;
    float val = 0.f;
    if (gr < NV){
      if (f < 3){
        val = pos[gr*3 + f];
      } else if (f < 27){
        const int g = (f-3)/6, rem = (f-3)%6;
        const int d = rem % 3;
        const float x = pos[gr*3 + d];
        const float fr = (float)(1 << g) * 3.14159265358979323846f;
        val = (rem < 3) ? sinf(fr*x) : cosf(fr*x);
      }
    }
    _Float16 h,m; split2(val,h,m);
    Af[0][r][f] = h; Af[1][r][f] = m;
  }
  __syncthreads();

  layer_run<1,  8192,false>(wp + 0,      b0, nullptr, Af, part, lane, wv);
  layer_run<8, 65536,false>(wp + 16384,  b1, nullptr, Af, part, lane, wv);
  layer_run<8, 65536,false>(wp + 147456, b2, nullptr, Af, part, lane, wv);
  layer_run<8, 65536,true >(wp + 278528, b3, wf,      Af, part, lane, wv);

  if (tid < ROWS && row0 + tid < NV){
    float s = part[tid][0] + part[tid][1] + part[tid][2] + part[tid][3];
    sdf[row0 + tid] = s + bf[0];
  }
}

// ---------------- scan helpers ----------------
__device__ __forceinline__ u32 wave_scan_incl(u32 v, int lane){
#pragma unroll
  for (int s=1;s<64;s<<=1){
    const u32 y = __shfl_up(v, s, 64);
    if (lane >= s) v += y;
  }
  return v;
}
__device__ __forceinline__ u32 block_scan_fast(u32 v, u32* sh4, int tid){
  const int lane = tid & 63, wv = tid >> 6;
  const u32 incl = wave_scan_incl(v, lane);
  if (lane == 63) sh4[wv] = incl;
  __syncthreads();
  u32 base = 0;
#pragma unroll
  for (int w=0;w<3;w++) if (w < wv) base += sh4[w];
  return incl + base;
}
__device__ __forceinline__ u64 bscan_u64(u64 v, u64* sh, int tid){
  sh[tid]=v; __syncthreads();
#pragma unroll
  for (int s=1;s<256;s<<=1){
    const u64 y = (tid>=s) ? sh[tid-s] : 0ull;
    __syncthreads();
    sh[tid] += y;
    __syncthreads();
  }
  return sh[tid];
}

// ---------------- K1: codes, in-block stable (n1,n2) scan, pair append ----------------
__global__ void tet_pairs(const int* __restrict__ tet, const float* __restrict__ sdf,
    unsigned char* __restrict__ codes, u32* __restrict__ tscan, u32* __restrict__ tsum,
    u32* __restrict__ segcur, u64* __restrict__ pairs)
{
  __shared__ u32 sh4[4];
  const int tid = threadIdx.x;
  const int t = blockIdx.x*256 + tid;
  const int4 v = *(const int4*)(&tet[4*t]);
  const int o0 = sdf[v.x] > 0.f;
  const int o1 = sdf[v.y] > 0.f;
  const int o2 = sdf[v.z] > 0.f;
  const int o3 = sdf[v.w] > 0.f;
  const int code = o0 | (o1<<1) | (o2<<2) | (o3<<3);
  codes[t] = (unsigned char)code;
  const int nt = c_ntri[code];
  if (nt > 0){
    const int vv[4] = {v.x, v.y, v.z, v.w};
    const int oc[4] = {o0,o1,o2,o3};
#pragma unroll
    for (int e=0;e<6;e++){
      const int ia = c_be[2*e], ib = c_be[2*e+1];
      if (oc[ia] != oc[ib]){
        const int p = vv[ia], q = vv[ib];
        const int lo = p<q ? p : q, hi = p<q ? q : p;
        const int seg = lo >> 10;
        const u32 slot = atomicAdd(&segcur[seg], 1u);
        if (slot < PCAP)
          pairs[(size_t)seg*PCAP + slot] = ((u64)(u32)lo << 32) | (u32)hi;
      }
    }
  }
  const u32 my = (u32)(nt==1) | ((u32)(nt==2)<<16);
  const u32 incl = block_scan_fast(my, sh4, tid);
  tscan[t] = incl - my;
  if (tid == 255) tsum[blockIdx.x] = incl;
}

// ---------------- K2: per-segment sort+dedup+index (blocks 0..195); tsum scan (block 196)
__global__ void seg_process(const u64* __restrict__ pairs_in, const u32* __restrict__ segcur,
    u64* __restrict__ uq, u32* __restrict__ ucnt, u32* __restrict__ ucnt_ex,
    u32* __restrict__ usum, const u32* __restrict__ tsum, u64* __restrict__ tsumE,
    u32* __restrict__ meta)
{
  const int tid = threadIdx.x;
  if (blockIdx.x == NSEGS){
    // scan tsum[3125] (packed u16 pairs) -> tsumE u64 exclusive (n1 lo32, n2 hi32)
    __shared__ u64 sh64[256];
    u64 loc[13]; u64 tot = 0ull;
#pragma unroll
    for (int i=0;i<13;i++){
      const int idx = tid*13 + i;
      const u32 p = (idx < NBLK) ? tsum[idx] : 0u;
      const u64 u = (u64)(p & 0xffffu) | ((u64)(p >> 16) << 32);
      loc[i] = u; tot += u;
    }
    const u64 incl = bscan_u64(tot, sh64, tid);
    u64 run = incl - tot;
#pragma unroll
    for (int i=0;i<13;i++){
      const int idx = tid*13 + i;
      if (idx < NBLK) tsumE[idx] = run;
      run += loc[i];
    }
    if (tid == 255){ meta[0] = (u32)(incl & 0xffffffffull); meta[1] = (u32)(incl >> 32); }
    return;
  }

  __shared__ u64 P[PCAP];         // 32 KB
  __shared__ u32 sh4[4];
  __shared__ u32 shbase;
  const int seg = blockIdx.x;
  int n = (int)segcur[seg];
  if (n > PCAP) n = PCAP;
  int np = 1; while (np < n) np <<= 1;

  for (int i=tid; i<np; i+=256)
    P[i] = (i < n) ? pairs_in[(size_t)seg*PCAP + i] : ~0ull;
  if (tid == 0) shbase = 0u;
  __syncthreads();

  // bitonic sort P[0..np)
  for (int k=2; k<=np; k<<=1){
    for (int j=k>>1; j>0; j>>=1){
      for (int i=tid; i<np; i+=256){
        const int ij = i ^ j;
        if (ij > i){
          const u64 a = P[i], b = P[ij];
          const bool up = ((i & k) == 0);
          if ((a > b) == up){ P[i] = b; P[ij] = a; }
        }
      }
      __syncthreads();
    }
  }

  // dedup + in-place left compaction (chunked; dest <= src, reads precede writes)
  for (int c=0; c<n; c+=256){
    const int i = c + tid;
    u64 key = 0ull; u32 f = 0u;
    if (i < n){
      key = P[i];
      f = (i == 0 || P[i] != P[i-1]) ? 1u : 0u;
    }
    __syncthreads();
    const u32 incl = block_scan_fast(f, sh4, tid);
    const u32 base = shbase;
    if (f) P[base + incl - 1u] = key;
    __syncthreads();
    if (tid == 255) shbase = base + incl;
    __syncthreads();
  }
  const int uc = (int)shbase;

  // write compacted unique (lo,hi) keys to global arena (overwrites pairs region)
  for (int i=tid; i<uc; i+=256) uq[(size_t)seg*PCAP + i] = P[i];

  // per-lo counts and segment-relative exclusive offsets via binary search in LDS
  const int lo0 = seg << 10;
  for (int c=0; c<1024; c+=256){
    const int lo = lo0 + c + tid;
    if (lo < NV){
      const u64 kl = (u64)(u32)lo << 32;
      const u64 kh = (u64)(u32)(lo+1) << 32;
      int a=0, b=uc;
      while (a < b){ const int m=(a+b)>>1; if (P[m] < kl) a=m+1; else b=m; }
      const int lb = a;
      b = uc;
      while (a < b){ const int m=(a+b)>>1; if (P[m] < kh) a=m+1; else b=m; }
      ucnt_ex[lo] = (u32)lb;
      ucnt[lo] = (u32)(a - lb);
    }
  }
  if (tid == 0) usum[seg] = (u32)uc;
}

// ---------------- K3: emit verts (blocks 0..195) + faces (blocks 196..3320) ----------------
__global__ void emit_all(const int* __restrict__ tet, const float* __restrict__ pos,
    const float* __restrict__ sdf, const unsigned char* __restrict__ codes,
    const u32* __restrict__ tscan, const u64* __restrict__ tsumE, const u32* __restrict__ meta,
    const u64* __restrict__ uq, const u32* __restrict__ ucnt, const u32* __restrict__ ucnt_ex,
    const u32* __restrict__ usum, float* __restrict__ out, int out_size)
{
  __shared__ u32 sh4[4];
  __shared__ u32 shu[NSEGS];
  __shared__ u32 shM;
  const int tid = threadIdx.x;
  {
    const u32 v = (tid < NSEGS) ? usum[tid] : 0u;
    const u32 incl = block_scan_fast(v, sh4, tid);
    if (tid < NSEGS) shu[tid] = incl - v;
    if (tid == NSEGS-1) shM = incl;
    __syncthreads();
  }

  if (blockIdx.x < NSEGS){
    const int seg = blockIdx.x;
    const int uc = (int)usum[seg];
    const u32 base = shu[seg];
    for (int i=tid; i<uc; i+=256){
      const u64 key = uq[(size_t)seg*PCAP + i];
      const int lo = (int)(key >> 32);
      const int hi = (int)(key & 0xffffffffull);
      const float s0 = sdf[lo], s1 = sdf[hi];
      const float d = s0 - s1;
      const float vx = (pos[3*lo  ]*(-s1) + pos[3*hi  ]*s0) / d;
      const float vy = (pos[3*lo+1]*(-s1) + pos[3*hi+1]*s0) / d;
      const float vz = (pos[3*lo+2]*(-s1) + pos[3*hi+2]*s0) / d;
      const long long w = 3ll*(long long)(base + (u32)i);
      if (w + 3 <= (long long)out_size){
        out[w] = vx; out[w+1] = vy; out[w+2] = vz;
      }
    }
  } else {
    const int t = (blockIdx.x - NSEGS)*256 + tid;   // 3125 blocks -> t < 800000 exactly
    const int code = codes[t];
    const int nt = c_ntri[code];
    if (nt == 0) return;
    const u64 tb = tsumE[t>>8];
    const u32 ts = tscan[t];
    const u32 n1e = (u32)(tb & 0xffffffffull) + (ts & 0xffffu);
    const u32 n2e = (u32)(tb >> 32) + (ts >> 16);
    const u32 N1 = meta[0];
    const u32 M  = shM;
    const u32 fb = (nt==1) ? n1e : (N1 + 2u*n2e);
    const int4 v = *(const int4*)(&tet[4*t]);
    const int vv[4] = {v.x, v.y, v.z, v.w};
    for (int r=0;r<nt;r++){
      for (int k=0;k<3;k++){
        const int e = c_tri[code][3*r+k];
        const int ia = c_be[2*e], ib = c_be[2*e+1];
        const int p = vv[ia], q = vv[ib];
        const int lo = p<q ? p : q, hi = p<q ? q : p;
        const int seg = lo >> 10;
        const u32 st = ucnt_ex[lo];
        const int u = (int)ucnt[lo];
        const u64* b = uq + (size_t)seg*PCAP + st;
        int id = -1;
        for (int j=0;j<u;j++){
          if ((int)(b[j] & 0xffffffffull) == hi){ id = (int)(shu[seg] + st) + j; break; }
        }
        const long long w = 3ll*(long long)M + 3ll*(long long)(fb + (u32)r) + k;
        if (w < (long long)out_size && id >= 0) out[w] = (float)id;
      }
    }
  }
}

// ---------------- launch: 5 dispatches ----------------
extern "C" void kernel_launch(void* const* d_in, const int* in_sizes, int n_in,
                              void* d_out, int out_size, void* d_ws, size_t ws_size,
                              hipStream_t stream)
{
  (void)in_sizes; (void)n_in; (void)ws_size;
  const float* pos = (const float*)d_in[0];
  const int*   tet = (const int*)d_in[1];
  const float* w0 = (const float*)d_in[2];
  const float* b0 = (const float*)d_in[3];
  const float* w1 = (const float*)d_in[4];
  const float* b1 = (const float*)d_in[5];
  const float* w2 = (const float*)d_in[6];
  const float* b2 = (const float*)d_in[7];
  const float* w3 = (const float*)d_in[8];
  const float* b3 = (const float*)d_in[9];
  const float* wf = (const float*)d_in[10];
  const float* bf = (const float*)d_in[11];
  float* out = (float*)d_out;
  char* ws = (char*)d_ws;

  float*         sdf   = (float*)(ws + 0);               // 800000 B
  unsigned char* codes = (unsigned char*)(ws + 800000);  // 800000 B
  u32* tscan   = (u32*)(ws + 1600000);                   // 3200000 B
  u32* tsum    = (u32*)(ws + 4800000);                   // 12800 B (3125 used)
  u64* tsumE   = (u64*)(ws + 4812800);                   // 25088 B (3125 used)
  u32* segcur  = (u32*)(ws + 4837888);                   // 1024 B (196 used)
  u32* usum    = (u32*)(ws + 4838912);                   // 1024 B
  u32* meta    = (u32*)(ws + 4839936);                   // 64 B
  u32* ucnt    = (u32*)(ws + 4840000);                   // 800000 B
  u32* ucnt_ex = (u32*)(ws + 5640000);                   // 800000 B
  _Float16* wp = (_Float16*)(ws + 6440000);              // 819200 B
  u64* pairs   = (u64*)(ws + 7259200);                   // 196*4096*8 = 6422528 B (reused as uq)
  // total ws: 13,681,728 B (< 17.6 MB proven available in prior rounds)

  split_weights<<<100,256,0,stream>>>(w0,w1,w2,w3,wp,segcur);
  mlp_mfma<<<MBLK,512,0,stream>>>(pos,wp,b0,b1,b2,b3,wf,bf,sdf);

  tet_pairs<<<NBLK,256,0,stream>>>(tet,sdf,codes,tscan,tsum,segcur,pairs);
  seg_process<<<NSEGS+1,256,0,stream>>>(pairs,segcur,pairs,ucnt,ucnt_ex,usum,tsum,tsumE,meta);
  emit_all<<<NSEGS+NBLK,256,0,stream>>>(tet,pos,sdf,codes,tscan,tsumE,meta,
                                        pairs,ucnt,ucnt_ex,usum,out,out_size);
}

// Round 6
// 446.771 us; speedup vs baseline: 1.1410x; 1.0649x over previous
//
#include <hip/hip_runtime.h>
#include <cstdint>
#include <cstddef>

#define NV 200000
#define NT 800000
#define ROWS 64
#define MBLK 3125   // 3125*64 = 200000 exactly
#define NBLK 3125   // 3125*256 = 800000 exactly (tet kernels)
#define NSEGS 196   // ceil(200000/1024) lo-segments
#define PCAP 4096   // pairs per segment arena (expected ~300; ~200 sigma margin)

typedef unsigned int u32;
typedef unsigned long long u64;

typedef __attribute__((ext_vector_type(8))) _Float16 half8;
typedef __attribute__((ext_vector_type(4))) float f32x4;
#define MFMA16F __builtin_amdgcn_mfma_f32_16x16x32_f16

// ---------------- marching-tets tables ----------------
__constant__ int c_tri[16][6] = {
  {-1,-1,-1,-1,-1,-1},{1,0,2,-1,-1,-1},{4,0,3,-1,-1,-1},{1,4,2,1,3,4},
  {3,1,5,-1,-1,-1},{2,3,0,2,5,3},{1,4,0,1,5,4},{4,2,5,-1,-1,-1},
  {4,5,2,-1,-1,-1},{4,1,0,4,5,1},{3,2,0,3,5,2},{1,3,5,-1,-1,-1},
  {4,1,2,4,3,1},{3,0,4,-1,-1,-1},{2,0,1,-1,-1,-1},{-1,-1,-1,-1,-1,-1}};
__constant__ int c_ntri[16] = {0,1,1,2,1,2,2,1,1,2,2,1,2,1,1,0};
__constant__ int c_be[12] = {0,1,0,2,0,3,1,2,1,3,2,3};

// ---------------- fp16 Dekker 2-way split: x ~= h + m*2^-11 ----------------
// PRECISION CONSTRAINT (derived r5): sdf error must stay ~2^-18 — the test only
// passes because no occupancy sign flips vs reference (min |sdf| over 200k
// samples ~1e-5). The 3-term Dekker (h*h + h*m' + m'*h) is REQUIRED; any
// lower-precision scheme flips signs -> topology change -> hard fail.
__device__ __forceinline__ void split2(float x, _Float16& h, _Float16& m){
  h = (_Float16)x;
  const float r = x - (float)h;
  m = (_Float16)(r * 2048.0f);
}

// ---------------- weight split prep + segment-cursor zeroing ----------------
__global__ void split_weights(const float* __restrict__ w0, const float* __restrict__ w1,
                              const float* __restrict__ w2, const float* __restrict__ w3,
                              _Float16* __restrict__ wp, u32* __restrict__ segcur)
{
  const int idx = blockIdx.x*256 + threadIdx.x;   // 0..204799
  if (idx < 256) segcur[idx] = 0u;
  int base, k, n, psz;
  float val;
  if (idx < 8192){                                  // layer0: K=27 padded to 32
    base = 0; psz = 8192; k = idx >> 8; n = idx & 255;
    val = (k < 27) ? w0[k*256 + n] : 0.f;
  } else {
    int r = idx - 8192;
    const int l = r >> 16;                          // 0..2 -> layers 1..3
    r &= 65535;
    k = r >> 8; n = r & 255; psz = 65536;
    base = 16384 + l*131072;
    const float* w = (l==0) ? w1 : (l==1) ? w2 : w3;
    val = w[k*256 + n];
  }
  _Float16 h, m; split2(val, h, m);
  const int c = k >> 5, kk = k & 31;
  const int off = (c*256 + n)*32 + kk;
  wp[base + off] = h;
  wp[base + psz + off] = m;
}

// ---------------- MFMA MLP (proven config: ROWS=64, lb(512,4), 2 blocks/CU, ~253 us)
// NOTE: gfx950 unified VGPR+AGPR file — 64 VGPR + 64 AGPR = 128 total = the 4-wave/SIMD
// budget exactly. Config-space lessons (r1-r5): 4 waves/SIMD mandatory (2/SIMD = +45us);
// R=64 rows/wave mandatory (R=32 doubles B-L2 traffic = +55us); bank conflicts are NOT
// a lever (18x reduction bought nothing); A-register-dbuf = null (compiler already does).
// This round's single change vs round-0: s_setprio(1) wrapped tightly around each
// 6-MFMA cluster (T5) — scheduler prefers MFMA-ready waves over load-issuing waves.
template<int NC, bool LAST>
__device__ __forceinline__ void layer_run(
    const _Float16* __restrict__ Wl, const float* __restrict__ Bv,
    const float* __restrict__ wfv,
    _Float16 (*Af)[ROWS][264], float (*part)[8],
    int lane, int wv)
{
  const int l15 = lane & 15, q = lane >> 4;
  const int col0 = wv * 32;
  f32x4 g0[4][2], g1[4][2];
#pragma unroll
  for (int i=0;i<4;i++)
#pragma unroll
    for (int j=0;j<2;j++){ g0[i][j] = (f32x4){0.f,0.f,0.f,0.f}; g1[i][j] = (f32x4){0.f,0.f,0.f,0.f}; }

  const _Float16* bp = Wl + (u32)((col0 + l15)*32 + q*8);
  half8 bA[2][2], bB[2][2];

  auto loadB = [&](int c, half8 (*dst)[2]){
#pragma unroll
    for (int p=0;p<2;p++)
#pragma unroll
      for (int nt=0;nt<2;nt++)
        dst[p][nt] = *(const half8*)(bp + (p*NC + c)*8192 + nt*512);
  };
  auto compute = [&](int c, const half8 (*bb)[2]){
#pragma unroll
    for (int mt=0;mt<4;mt++){
      const _Float16* ap = &Af[0][mt*16 + l15][c*32 + q*8];
      const half8 ah = *(const half8*)(ap);
      const half8 am = *(const half8*)(ap + ROWS*264);
      __builtin_amdgcn_s_setprio(1);
#pragma unroll
      for (int nt=0;nt<2;nt++){
        g0[mt][nt] = MFMA16F(ah, bb[0][nt], g0[mt][nt], 0,0,0);   // h*h
        g1[mt][nt] = MFMA16F(ah, bb[1][nt], g1[mt][nt], 0,0,0);   // h*m'
        g1[mt][nt] = MFMA16F(am, bb[0][nt], g1[mt][nt], 0,0,0);   // m'*h
      }
      __builtin_amdgcn_s_setprio(0);
    }
  };

  loadB(0, bA);
  if (NC == 1){
    compute(0, bA);
  } else {
#pragma unroll 1
    for (int ch=0; ch<NC/2; ch++){
      const int c0 = 2*ch;
      loadB(c0+1, bB);
      compute(c0, bA);
      if (c0+2 < NC) loadB(c0+2, bA);
      compute(c0+1, bB);
    }
  }
  __syncthreads();

  const float S = 4.8828125e-4f;         // 2^-11
  if (!LAST){
#pragma unroll
    for (int nt=0;nt<2;nt++){
      const int col = col0 + nt*16 + l15;
      const float bias = Bv[col];
#pragma unroll
      for (int mt=0;mt<4;mt++)
#pragma unroll
        for (int reg=0;reg<4;reg++){
          const int row = mt*16 + q*4 + reg;
          const float v = fmaxf(g0[mt][nt][reg] + S*g1[mt][nt][reg] + bias, 0.f);
          _Float16 h,m; split2(v,h,m);
          Af[0][row][col] = h; Af[1][row][col] = m;
        }
    }
  } else {
    float pr[4][4];
#pragma unroll
    for (int mt=0;mt<4;mt++)
#pragma unroll
      for (int reg=0;reg<4;reg++) pr[mt][reg] = 0.f;
#pragma unroll
    for (int nt=0;nt<2;nt++){
      const int col = col0 + nt*16 + l15;
      const float bias = Bv[col];
      const float w = wfv[col];
#pragma unroll
      for (int mt=0;mt<4;mt++)
#pragma unroll
        for (int reg=0;reg<4;reg++)
          pr[mt][reg] += fmaxf(g0[mt][nt][reg] + S*g1[mt][nt][reg] + bias, 0.f) * w;
    }
#pragma unroll
    for (int s=1;s<16;s<<=1)
#pragma unroll
      for (int mt=0;mt<4;mt++)
#pragma unroll
        for (int reg=0;reg<4;reg++)
          pr[mt][reg] += __shfl_xor(pr[mt][reg], s, 64);
    if (l15 == 0){
#pragma unroll
      for (int mt=0;mt<4;mt++)
#pragma unroll
        for (int reg=0;reg<4;reg++)
          part[mt*16 + q*4 + reg][wv] = pr[mt][reg];
    }
  }
  __syncthreads();
}

__global__ __launch_bounds__(512,4) void mlp_mfma(
    const float* __restrict__ pos, const _Float16* __restrict__ wp,
    const float* __restrict__ b0, const float* __restrict__ b1,
    const float* __restrict__ b2, const float* __restrict__ b3,
    const float* __restrict__ wf, const float* __restrict__ bf,
    float* __restrict__ sdf)
{
  __shared__ _Float16 Af[2][ROWS][264];    // 67,584 B
  __shared__ float part[ROWS][8];          // 2,048 B -> 69.6 KB = 2 blocks/CU
  const int tid = threadIdx.x;
  const int lane = tid & 63, wv = tid >> 6;
  const int row0 = blockIdx.x * ROWS;

#pragma unroll
  for (int it=0; it<4; it++){
    const int idx = it*512 + tid;          // 2048 = 64 rows x 32 k
    const int r = idx & 63, f = idx >> 6;
    float val = 0.f;
    if (f < 3){
      val = pos[(row0 + r)*3 + f];
    } else if (f < 27){
      const int g = (f-3)/6, rem = (f-3)%6;
      const int d = rem % 3;
      const float x = pos[(row0 + r)*3 + d];
      const float fr = (float)(1 << g) * 3.14159265358979323846f;
      val = (rem < 3) ? sinf(fr*x) : cosf(fr*x);
    }
    _Float16 h,m; split2(val,h,m);
    Af[0][r][f] = h; Af[1][r][f] = m;
  }
  __syncthreads();

  layer_run<1,false>(wp + 0,      b0, nullptr, Af, part, lane, wv);
  layer_run<8,false>(wp + 16384,  b1, nullptr, Af, part, lane, wv);
  layer_run<8,false>(wp + 147456, b2, nullptr, Af, part, lane, wv);
  layer_run<8,true >(wp + 278528, b3, wf,      Af, part, lane, wv);

  if (tid < ROWS){
    float s = 0.f;
#pragma unroll
    for (int w=0; w<8; w++) s += part[tid][w];
    sdf[row0 + tid] = s + bf[0];
  }
}

// ---------------- scan helpers ----------------
__device__ __forceinline__ u32 wave_scan_incl(u32 v, int lane){
#pragma unroll
  for (int s=1;s<64;s<<=1){
    const u32 y = __shfl_up(v, s, 64);
    if (lane >= s) v += y;
  }
  return v;
}
__device__ __forceinline__ u32 block_scan_fast(u32 v, u32* sh4, int tid){
  const int lane = tid & 63, wv = tid >> 6;
  const u32 incl = wave_scan_incl(v, lane);
  if (lane == 63) sh4[wv] = incl;
  __syncthreads();
  u32 base = 0;
#pragma unroll
  for (int w=0;w<3;w++) if (w < wv) base += sh4[w];
  return incl + base;
}
__device__ __forceinline__ u64 bscan_u64(u64 v, u64* sh, int tid){
  sh[tid]=v; __syncthreads();
#pragma unroll
  for (int s=1;s<256;s<<=1){
    const u64 y = (tid>=s) ? sh[tid-s] : 0ull;
    __syncthreads();
    sh[tid] += y;
    __syncthreads();
  }
  return sh[tid];
}

// ---------------- K1: codes, in-block stable (n1,n2) scan, pair append ----------------
__global__ void tet_pairs(const int* __restrict__ tet, const float* __restrict__ sdf,
    unsigned char* __restrict__ codes, u32* __restrict__ tscan, u32* __restrict__ tsum,
    u32* __restrict__ segcur, u64* __restrict__ pairs)
{
  __shared__ u32 sh4[4];
  const int tid = threadIdx.x;
  const int t = blockIdx.x*256 + tid;
  const int4 v = *(const int4*)(&tet[4*t]);
  const int o0 = sdf[v.x] > 0.f;
  const int o1 = sdf[v.y] > 0.f;
  const int o2 = sdf[v.z] > 0.f;
  const int o3 = sdf[v.w] > 0.f;
  const int code = o0 | (o1<<1) | (o2<<2) | (o3<<3);
  codes[t] = (unsigned char)code;
  const int nt = c_ntri[code];
  if (nt > 0){
    const int vv[4] = {v.x, v.y, v.z, v.w};
    const int oc[4] = {o0,o1,o2,o3};
#pragma unroll
    for (int e=0;e<6;e++){
      const int ia = c_be[2*e], ib = c_be[2*e+1];
      if (oc[ia] != oc[ib]){
        const int p = vv[ia], q = vv[ib];
        const int lo = p<q ? p : q, hi = p<q ? q : p;
        const int seg = lo >> 10;
        const u32 slot = atomicAdd(&segcur[seg], 1u);
        if (slot < PCAP)
          pairs[(size_t)seg*PCAP + slot] = ((u64)(u32)lo << 32) | (u32)hi;
      }
    }
  }
  const u32 my = (u32)(nt==1) | ((u32)(nt==2)<<16);
  const u32 incl = block_scan_fast(my, sh4, tid);
  tscan[t] = incl - my;
  if (tid == 255) tsum[blockIdx.x] = incl;
}

// ---------------- K2: per-segment sort+dedup+index (blocks 0..195); tsum scan (block 196)
__global__ void seg_process(const u64* __restrict__ pairs_in, const u32* __restrict__ segcur,
    u64* __restrict__ uq, u32* __restrict__ ucnt, u32* __restrict__ ucnt_ex,
    u32* __restrict__ usum, const u32* __restrict__ tsum, u64* __restrict__ tsumE,
    u32* __restrict__ meta)
{
  const int tid = threadIdx.x;
  if (blockIdx.x == NSEGS){
    // scan tsum[3125] (packed u16 pairs) -> tsumE u64 exclusive (n1 lo32, n2 hi32)
    __shared__ u64 sh64[256];
    u64 loc[13]; u64 tot = 0ull;
#pragma unroll
    for (int i=0;i<13;i++){
      const int idx = tid*13 + i;
      const u32 p = (idx < NBLK) ? tsum[idx] : 0u;
      const u64 u = (u64)(p & 0xffffu) | ((u64)(p >> 16) << 32);
      loc[i] = u; tot += u;
    }
    const u64 incl = bscan_u64(tot, sh64, tid);
    u64 run = incl - tot;
#pragma unroll
    for (int i=0;i<13;i++){
      const int idx = tid*13 + i;
      if (idx < NBLK) tsumE[idx] = run;
      run += loc[i];
    }
    if (tid == 255){ meta[0] = (u32)(incl & 0xffffffffull); meta[1] = (u32)(incl >> 32); }
    return;
  }

  __shared__ u64 P[PCAP];         // 32 KB
  __shared__ u32 sh4[4];
  __shared__ u32 shbase;
  const int seg = blockIdx.x;
  int n = (int)segcur[seg];
  if (n > PCAP) n = PCAP;
  int np = 1; while (np < n) np <<= 1;

  for (int i=tid; i<np; i+=256)
    P[i] = (i < n) ? pairs_in[(size_t)seg*PCAP + i] : ~0ull;
  if (tid == 0) shbase = 0u;
  __syncthreads();

  // bitonic sort P[0..np)
  for (int k=2; k<=np; k<<=1){
    for (int j=k>>1; j>0; j>>=1){
      for (int i=tid; i<np; i+=256){
        const int ij = i ^ j;
        if (ij > i){
          const u64 a = P[i], b = P[ij];
          const bool up = ((i & k) == 0);
          if ((a > b) == up){ P[i] = b; P[ij] = a; }
        }
      }
      __syncthreads();
    }
  }

  // dedup + in-place left compaction (chunked; dest <= src, reads precede writes)
  for (int c=0; c<n; c+=256){
    const int i = c + tid;
    u64 key = 0ull; u32 f = 0u;
    if (i < n){
      key = P[i];
      f = (i == 0 || P[i] != P[i-1]) ? 1u : 0u;
    }
    __syncthreads();
    const u32 incl = block_scan_fast(f, sh4, tid);
    const u32 base = shbase;
    if (f) P[base + incl - 1u] = key;
    __syncthreads();
    if (tid == 255) shbase = base + incl;
    __syncthreads();
  }
  const int uc = (int)shbase;

  // write compacted unique (lo,hi) keys to global arena (overwrites pairs region)
  for (int i=tid; i<uc; i+=256) uq[(size_t)seg*PCAP + i] = P[i];

  // per-lo counts and segment-relative exclusive offsets via binary search in LDS
  const int lo0 = seg << 10;
  for (int c=0; c<1024; c+=256){
    const int lo = lo0 + c + tid;
    if (lo < NV){
      const u64 kl = (u64)(u32)lo << 32;
      const u64 kh = (u64)(u32)(lo+1) << 32;
      int a=0, b=uc;
      while (a < b){ const int m=(a+b)>>1; if (P[m] < kl) a=m+1; else b=m; }
      const int lb = a;
      b = uc;
      while (a < b){ const int m=(a+b)>>1; if (P[m] < kh) a=m+1; else b=m; }
      ucnt_ex[lo] = (u32)lb;
      ucnt[lo] = (u32)(a - lb);
    }
  }
  if (tid == 0) usum[seg] = (u32)uc;
}

// ---------------- K3: emit verts (blocks 0..195) + faces (blocks 196..3320) ----------------
__global__ void emit_all(const int* __restrict__ tet, const float* __restrict__ pos,
    const float* __restrict__ sdf, const unsigned char* __restrict__ codes,
    const u32* __restrict__ tscan, const u64* __restrict__ tsumE, const u32* __restrict__ meta,
    const u64* __restrict__ uq, const u32* __restrict__ ucnt, const u32* __restrict__ ucnt_ex,
    const u32* __restrict__ usum, float* __restrict__ out, int out_size)
{
  __shared__ u32 sh4[4];
  __shared__ u32 shu[NSEGS];
  __shared__ u32 shM;
  const int tid = threadIdx.x;
  {
    const u32 v = (tid < NSEGS) ? usum[tid] : 0u;
    const u32 incl = block_scan_fast(v, sh4, tid);
    if (tid < NSEGS) shu[tid] = incl - v;
    if (tid == NSEGS-1) shM = incl;
    __syncthreads();
  }

  if (blockIdx.x < NSEGS){
    const int seg = blockIdx.x;
    const int uc = (int)usum[seg];
    const u32 base = shu[seg];
    for (int i=tid; i<uc; i+=256){
      const u64 key = uq[(size_t)seg*PCAP + i];
      const int lo = (int)(key >> 32);
      const int hi = (int)(key & 0xffffffffull);
      const float s0 = sdf[lo], s1 = sdf[hi];
      const float d = s0 - s1;
      const float vx = (pos[3*lo  ]*(-s1) + pos[3*hi  ]*s0) / d;
      const float vy = (pos[3*lo+1]*(-s1) + pos[3*hi+1]*s0) / d;
      const float vz = (pos[3*lo+2]*(-s1) + pos[3*hi+2]*s0) / d;
      const long long w = 3ll*(long long)(base + (u32)i);
      if (w + 3 <= (long long)out_size){
        out[w] = vx; out[w+1] = vy; out[w+2] = vz;
      }
    }
  } else {
    const int t = (blockIdx.x - NSEGS)*256 + tid;   // 3125 blocks -> t < 800000 exactly
    const int code = codes[t];
    const int nt = c_ntri[code];
    if (nt == 0) return;
    const u64 tb = tsumE[t>>8];
    const u32 ts = tscan[t];
    const u32 n1e = (u32)(tb & 0xffffffffull) + (ts & 0xffffu);
    const u32 n2e = (u32)(tb >> 32) + (ts >> 16);
    const u32 N1 = meta[0];
    const u32 M  = shM;
    const u32 fb = (nt==1) ? n1e : (N1 + 2u*n2e);
    const int4 v = *(const int4*)(&tet[4*t]);
    const int vv[4] = {v.x, v.y, v.z, v.w};
    for (int r=0;r<nt;r++){
      for (int k=0;k<3;k++){
        const int e = c_tri[code][3*r+k];
        const int ia = c_be[2*e], ib = c_be[2*e+1];
        const int p = vv[ia], q = vv[ib];
        const int lo = p<q ? p : q, hi = p<q ? q : p;
        const int seg = lo >> 10;
        const u32 st = ucnt_ex[lo];
        const int u = (int)ucnt[lo];
        const u64* b = uq + (size_t)seg*PCAP + st;
        int id = -1;
        for (int j=0;j<u;j++){
          if ((int)(b[j] & 0xffffffffull) == hi){ id = (int)(shu[seg] + st) + j; break; }
        }
        const long long w = 3ll*(long long)M + 3ll*(long long)(fb + (u32)r) + k;
        if (w < (long long)out_size && id >= 0) out[w] = (float)id;
      }
    }
  }
}

// ---------------- launch: 5 dispatches ----------------
extern "C" void kernel_launch(void* const* d_in, const int* in_sizes, int n_in,
                              void* d_out, int out_size, void* d_ws, size_t ws_size,
                              hipStream_t stream)
{
  (void)in_sizes; (void)n_in; (void)ws_size;
  const float* pos = (const float*)d_in[0];
  const int*   tet = (const int*)d_in[1];
  const float* w0 = (const float*)d_in[2];
  const float* b0 = (const float*)d_in[3];
  const float* w1 = (const float*)d_in[4];
  const float* b1 = (const float*)d_in[5];
  const float* w2 = (const float*)d_in[6];
  const float* b2 = (const float*)d_in[7];
  const float* w3 = (const float*)d_in[8];
  const float* b3 = (const float*)d_in[9];
  const float* wf = (const float*)d_in[10];
  const float* bf = (const float*)d_in[11];
  float* out = (float*)d_out;
  char* ws = (char*)d_ws;

  float*         sdf   = (float*)(ws + 0);               // 800000 B
  unsigned char* codes = (unsigned char*)(ws + 800000);  // 800000 B
  u32* tscan   = (u32*)(ws + 1600000);                   // 3200000 B
  u32* tsum    = (u32*)(ws + 4800000);                   // 12800 B (3125 used)
  u64* tsumE   = (u64*)(ws + 4812800);                   // 25088 B (3125 used)
  u32* segcur  = (u32*)(ws + 4837888);                   // 1024 B (196 used)
  u32* usum    = (u32*)(ws + 4838912);                   // 1024 B
  u32* meta    = (u32*)(ws + 4839936);                   // 64 B
  u32* ucnt    = (u32*)(ws + 4840000);                   // 800000 B
  u32* ucnt_ex = (u32*)(ws + 5640000);                   // 800000 B
  _Float16* wp = (_Float16*)(ws + 6440000);              // 819200 B
  u64* pairs   = (u64*)(ws + 7259200);                   // 196*4096*8 = 6422528 B (reused as uq)
  // total ws: 13,681,728 B (< 17.6 MB proven available in prior rounds)

  split_weights<<<800,256,0,stream>>>(w0,w1,w2,w3,wp,segcur);
  mlp_mfma<<<MBLK,512,0,stream>>>(pos,wp,b0,b1,b2,b3,wf,bf,sdf);

  tet_pairs<<<NBLK,256,0,stream>>>(tet,sdf,codes,tscan,tsum,segcur,pairs);
  seg_process<<<NSEGS+1,256,0,stream>>>(pairs,segcur,pairs,ucnt,ucnt_ex,usum,tsum,tsumE,meta);
  emit_all<<<NSEGS+NBLK,256,0,stream>>>(tet,pos,sdf,codes,tscan,tsumE,meta,
                                        pairs,ucnt,ucnt_ex,usum,out,out_size);
}

// Round 8
// 441.354 us; speedup vs baseline: 1.1550x; 1.0123x over previous
//
#include <hip/hip_runtime.h>
#include <cstdint>
#include <cstddef>

#define NV 200000
#define NT 800000
#define ROWS 64
#define MAINB 3072   // 3072*64 = 196608 rows; exactly 6 rounds of 512 resident blocks
#define TAILB 212    // 212*16  = 3392 rows; cheap 16-row blocks fill the 7th round
#define MBLK (MAINB+TAILB)
#define NBLK 3125   // 3125*256 = 800000 exactly (tet kernels)
#define NSEGS 196   // ceil(200000/1024) lo-segments
#define PCAP 4096   // pairs per segment arena (expected ~300; ~200 sigma margin)

typedef unsigned int u32;
typedef unsigned long long u64;

typedef __attribute__((ext_vector_type(8))) _Float16 half8;
typedef __attribute__((ext_vector_type(4))) float f32x4;
#define MFMA16F __builtin_amdgcn_mfma_f32_16x16x32_f16

// ---------------- marching-tets tables ----------------
__constant__ int c_tri[16][6] = {
  {-1,-1,-1,-1,-1,-1},{1,0,2,-1,-1,-1},{4,0,3,-1,-1,-1},{1,4,2,1,3,4},
  {3,1,5,-1,-1,-1},{2,3,0,2,5,3},{1,4,0,1,5,4},{4,2,5,-1,-1,-1},
  {4,5,2,-1,-1,-1},{4,1,0,4,5,1},{3,2,0,3,5,2},{1,3,5,-1,-1,-1},
  {4,1,2,4,3,1},{3,0,4,-1,-1,-1},{2,0,1,-1,-1,-1},{-1,-1,-1,-1,-1,-1}};
__constant__ int c_ntri[16] = {0,1,1,2,1,2,2,1,1,2,2,1,2,1,1,0};
__constant__ int c_be[12] = {0,1,0,2,0,3,1,2,1,3,2,3};

// ---------------- fp16 Dekker 2-way split: x ~= h + m*2^-11 ----------------
// PRECISION CONSTRAINT (derived r5): sdf error must stay ~2^-18. The 3-term
// Dekker (h*h + h*m' + m'*h) is REQUIRED; lower precision flips occupancy
// signs -> topology change -> hard fail. 3x MFMA multiplier is structural.
__device__ __forceinline__ void split2(float x, _Float16& h, _Float16& m){
  h = (_Float16)x;
  const float r = x - (float)h;
  m = (_Float16)(r * 2048.0f);
}

// ---------------- weight split prep + segment-cursor zeroing ----------------
__global__ void split_weights(const float* __restrict__ w0, const float* __restrict__ w1,
                              const float* __restrict__ w2, const float* __restrict__ w3,
                              _Float16* __restrict__ wp, u32* __restrict__ segcur)
{
  const int idx = blockIdx.x*256 + threadIdx.x;   // 0..204799
  if (idx < 256) segcur[idx] = 0u;
  int base, k, n, psz;
  float val;
  if (idx < 8192){                                  // layer0: K=27 padded to 32
    base = 0; psz = 8192; k = idx >> 8; n = idx & 255;
    val = (k < 27) ? w0[k*256 + n] : 0.f;
  } else {
    int r = idx - 8192;
    const int l = r >> 16;                          // 0..2 -> layers 1..3
    r &= 65535;
    k = r >> 8; n = r & 255; psz = 65536;
    base = 16384 + l*131072;
    const float* w = (l==0) ? w1 : (l==1) ? w2 : w3;
    val = w[k*256 + n];
  }
  _Float16 h, m; split2(val, h, m);
  const int c = k >> 5, kk = k & 31;
  const int off = (c*256 + n)*32 + kk;
  wp[base + off] = h;
  wp[base + psz + off] = m;
}

// ---------------- MFMA MLP (proven r0 config + mixed-size grid tail) ----------
// Occupancy accounting (r6): MfmaUtil 45% = 92% of occupancy-adjusted potential;
// in-layer stalls ~8%. Losses: reg cap (128 regs -> 16 waves/CU, irreducible:
// acc=64 AGPR min at R=64/C=32; R<64 hits L2-BW wall) and the GRID TAIL
// (3125 blocks / 512 slots = 6.10 -> makespan 7 rounds). Fix: 3072 full blocks
// (6 exact rounds) + 212 cheap 16-row blocks (MT=1) filling the 7th round.
// MT = number of 16-row M-tiles per block (4 = main, 1 = tail).
template<int MT, int NC, bool LAST>
__device__ __forceinline__ void layer_run(
    const _Float16* __restrict__ Wl, const float* __restrict__ Bv,
    const float* __restrict__ wfv,
    _Float16* __restrict__ Af, float (*part)[8],
    int lane, int wv)
{
  const int l15 = lane & 15, q = lane >> 4;
  const int col0 = wv * 32;
  constexpr u32 PSTl = (u32)(MT*16*264);    // plane stride (h-plane -> m-plane)
  f32x4 g0[MT][2], g1[MT][2];
#pragma unroll
  for (int i=0;i<MT;i++)
#pragma unroll
    for (int j=0;j<2;j++){ g0[i][j] = (f32x4){0.f,0.f,0.f,0.f}; g1[i][j] = (f32x4){0.f,0.f,0.f,0.f}; }

  const _Float16* bp = Wl + (u32)((col0 + l15)*32 + q*8);
  half8 bA[2][2], bB[2][2];

  auto loadB = [&](int c, half8 (*dst)[2]){
#pragma unroll
    for (int p=0;p<2;p++)
#pragma unroll
      for (int nt=0;nt<2;nt++)
        dst[p][nt] = *(const half8*)(bp + (p*NC + c)*8192 + nt*512);
  };
  auto compute = [&](int c, const half8 (*bb)[2]){
#pragma unroll
    for (int mt=0;mt<MT;mt++){
      const _Float16* ap = Af + (u32)((mt*16 + l15)*264 + c*32 + q*8);
      const half8 ah = *(const half8*)(ap);
      const half8 am = *(const half8*)(ap + PSTl);
#pragma unroll
      for (int nt=0;nt<2;nt++){
        g0[mt][nt] = MFMA16F(ah, bb[0][nt], g0[mt][nt], 0,0,0);   // h*h
        g1[mt][nt] = MFMA16F(ah, bb[1][nt], g1[mt][nt], 0,0,0);   // h*m'
        g1[mt][nt] = MFMA16F(am, bb[0][nt], g1[mt][nt], 0,0,0);   // m'*h
      }
    }
  };

  loadB(0, bA);
  if (NC == 1){
    compute(0, bA);
  } else {
#pragma unroll 1
    for (int ch=0; ch<NC/2; ch++){
      const int c0 = 2*ch;
      loadB(c0+1, bB);
      compute(c0, bA);
      if (c0+2 < NC) loadB(c0+2, bA);
      compute(c0+1, bB);
    }
  }
  __syncthreads();

  const float S = 4.8828125e-4f;         // 2^-11
  if (!LAST){
#pragma unroll
    for (int nt=0;nt<2;nt++){
      const int col = col0 + nt*16 + l15;
      const float bias = Bv[col];
#pragma unroll
      for (int mt=0;mt<MT;mt++)
#pragma unroll
        for (int reg=0;reg<4;reg++){
          const int row = mt*16 + q*4 + reg;
          const float v = fmaxf(g0[mt][nt][reg] + S*g1[mt][nt][reg] + bias, 0.f);
          _Float16 h,m; split2(v,h,m);
          Af[(u32)(row*264 + col)] = h;
          Af[PSTl + (u32)(row*264 + col)] = m;
        }
    }
  } else {
    float pr[MT][4];
#pragma unroll
    for (int mt=0;mt<MT;mt++)
#pragma unroll
      for (int reg=0;reg<4;reg++) pr[mt][reg] = 0.f;
#pragma unroll
    for (int nt=0;nt<2;nt++){
      const int col = col0 + nt*16 + l15;
      const float bias = Bv[col];
      const float w = wfv[col];
#pragma unroll
      for (int mt=0;mt<MT;mt++)
#pragma unroll
        for (int reg=0;reg<4;reg++)
          pr[mt][reg] += fmaxf(g0[mt][nt][reg] + S*g1[mt][nt][reg] + bias, 0.f) * w;
    }
#pragma unroll
    for (int s=1;s<16;s<<=1)
#pragma unroll
      for (int mt=0;mt<MT;mt++)
#pragma unroll
        for (int reg=0;reg<4;reg++)
          pr[mt][reg] += __shfl_xor(pr[mt][reg], s, 64);
    if (l15 == 0){
#pragma unroll
      for (int mt=0;mt<MT;mt++)
#pragma unroll
        for (int reg=0;reg<4;reg++)
          part[mt*16 + q*4 + reg][wv] = pr[mt][reg];
    }
  }
  __syncthreads();
}

__device__ __forceinline__ float posenc_val(const float* __restrict__ pos, int gr, int f){
  if (f < 3) return pos[gr*3 + f];
  if (f < 27){
    const int g = (f-3)/6, rem = (f-3)%6;
    const int d = rem % 3;
    const float x = pos[gr*3 + d];
    const float fr = (float)(1 << g) * 3.14159265358979323846f;
    return (rem < 3) ? sinf(fr*x) : cosf(fr*x);
  }
  return 0.f;
}

__global__ __launch_bounds__(512,4) void mlp_mfma(
    const float* __restrict__ pos, const _Float16* __restrict__ wp,
    const float* __restrict__ b0, const float* __restrict__ b1,
    const float* __restrict__ b2, const float* __restrict__ b3,
    const float* __restrict__ wf, const float* __restrict__ bf,
    float* __restrict__ sdf)
{
  __shared__ _Float16 Af[2*ROWS*264];      // 67,584 B (flat; tail uses 2*16*264 prefix)
  __shared__ float part[ROWS][8];          // 2,048 B -> 69.6 KB = 2 blocks/CU
  const int tid = threadIdx.x;
  const int lane = tid & 63, wv = tid >> 6;
  const int bid = blockIdx.x;

  if (bid < MAINB){
    const int row0 = bid * ROWS;
#pragma unroll
    for (int it=0; it<4; it++){
      const int idx = it*512 + tid;        // 2048 = 64 rows x 32 k
      const int r = idx & 63, f = idx >> 6;
      const float val = posenc_val(pos, row0 + r, f);
      _Float16 h,m; split2(val,h,m);
      Af[(u32)(r*264 + f)] = h;
      Af[(u32)(ROWS*264 + r*264 + f)] = m;
    }
    __syncthreads();

    layer_run<4,1,false>(wp + 0,      b0, nullptr, Af, part, lane, wv);
    layer_run<4,8,false>(wp + 16384,  b1, nullptr, Af, part, lane, wv);
    layer_run<4,8,false>(wp + 147456, b2, nullptr, Af, part, lane, wv);
    layer_run<4,8,true >(wp + 278528, b3, wf,      Af, part, lane, wv);

    if (tid < ROWS){
      float s = 0.f;
#pragma unroll
      for (int w=0; w<8; w++) s += part[tid][w];
      sdf[row0 + tid] = s + bf[0];
    }
  } else {
    const int row0 = MAINB*ROWS + (bid - MAINB) * 16;
    {
      const int r = tid & 15, f = tid >> 4;  // 512 = 16 rows x 32 k
      const float val = posenc_val(pos, row0 + r, f);
      _Float16 h,m; split2(val,h,m);
      Af[(u32)(r*264 + f)] = h;
      Af[(u32)(16*264 + r*264 + f)] = m;
    }
    __syncthreads();

    layer_run<1,1,false>(wp + 0,      b0, nullptr, Af, part, lane, wv);
    layer_run<1,8,false>(wp + 16384,  b1, nullptr, Af, part, lane, wv);
    layer_run<1,8,false>(wp + 147456, b2, nullptr, Af, part, lane, wv);
    layer_run<1,8,true >(wp + 278528, b3, wf,      Af, part, lane, wv);

    if (tid < 16){
      float s = 0.f;
#pragma unroll
      for (int w=0; w<8; w++) s += part[tid][w];
      sdf[row0 + tid] = s + bf[0];
    }
  }
}

// ---------------- scan helpers ----------------
__device__ __forceinline__ u32 wave_scan_incl(u32 v, int lane){
#pragma unroll
  for (int s=1;s<64;s<<=1){
    const u32 y = __shfl_up(v, s, 64);
    if (lane >= s) v += y;
  }
  return v;
}
__device__ __forceinline__ u32 block_scan_fast(u32 v, u32* sh4, int tid){
  const int lane = tid & 63, wv = tid >> 6;
  const u32 incl = wave_scan_incl(v, lane);
  if (lane == 63) sh4[wv] = incl;
  __syncthreads();
  u32 base = 0;
#pragma unroll
  for (int w=0;w<3;w++) if (w < wv) base += sh4[w];
  return incl + base;
}
__device__ __forceinline__ u64 bscan_u64(u64 v, u64* sh, int tid){
  sh[tid]=v; __syncthreads();
#pragma unroll
  for (int s=1;s<256;s<<=1){
    const u64 y = (tid>=s) ? sh[tid-s] : 0ull;
    __syncthreads();
    sh[tid] += y;
    __syncthreads();
  }
  return sh[tid];
}

// ---------------- K1: codes, in-block stable (n1,n2) scan, pair append ----------------
__global__ void tet_pairs(const int* __restrict__ tet, const float* __restrict__ sdf,
    unsigned char* __restrict__ codes, u32* __restrict__ tscan, u32* __restrict__ tsum,
    u32* __restrict__ segcur, u64* __restrict__ pairs)
{
  __shared__ u32 sh4[4];
  const int tid = threadIdx.x;
  const int t = blockIdx.x*256 + tid;
  const int4 v = *(const int4*)(&tet[4*t]);
  const int o0 = sdf[v.x] > 0.f;
  const int o1 = sdf[v.y] > 0.f;
  const int o2 = sdf[v.z] > 0.f;
  const int o3 = sdf[v.w] > 0.f;
  const int code = o0 | (o1<<1) | (o2<<2) | (o3<<3);
  codes[t] = (unsigned char)code;
  const int nt = c_ntri[code];
  if (nt > 0){
    const int vv[4] = {v.x, v.y, v.z, v.w};
    const int oc[4] = {o0,o1,o2,o3};
#pragma unroll
    for (int e=0;e<6;e++){
      const int ia = c_be[2*e], ib = c_be[2*e+1];
      if (oc[ia] != oc[ib]){
        const int p = vv[ia], q = vv[ib];
        const int lo = p<q ? p : q, hi = p<q ? q : p;
        const int seg = lo >> 10;
        const u32 slot = atomicAdd(&segcur[seg], 1u);
        if (slot < PCAP)
          pairs[(size_t)seg*PCAP + slot] = ((u64)(u32)lo << 32) | (u32)hi;
      }
    }
  }
  const u32 my = (u32)(nt==1) | ((u32)(nt==2)<<16);
  const u32 incl = block_scan_fast(my, sh4, tid);
  tscan[t] = incl - my;
  if (tid == 255) tsum[blockIdx.x] = incl;
}

// ---------------- K2: per-segment sort+dedup+index (blocks 0..195); tsum scan (block 196)
__global__ void seg_process(const u64* __restrict__ pairs_in, const u32* __restrict__ segcur,
    u64* __restrict__ uq, u32* __restrict__ ucnt, u32* __restrict__ ucnt_ex,
    u32* __restrict__ usum, const u32* __restrict__ tsum, u64* __restrict__ tsumE,
    u32* __restrict__ meta)
{
  const int tid = threadIdx.x;
  if (blockIdx.x == NSEGS){
    // scan tsum[3125] (packed u16 pairs) -> tsumE u64 exclusive (n1 lo32, n2 hi32)
    __shared__ u64 sh64[256];
    u64 loc[13]; u64 tot = 0ull;
#pragma unroll
    for (int i=0;i<13;i++){
      const int idx = tid*13 + i;
      const u32 p = (idx < NBLK) ? tsum[idx] : 0u;
      const u64 u = (u64)(p & 0xffffu) | ((u64)(p >> 16) << 32);
      loc[i] = u; tot += u;
    }
    const u64 incl = bscan_u64(tot, sh64, tid);
    u64 run = incl - tot;
#pragma unroll
    for (int i=0;i<13;i++){
      const int idx = tid*13 + i;
      if (idx < NBLK) tsumE[idx] = run;
      run += loc[i];
    }
    if (tid == 255){ meta[0] = (u32)(incl & 0xffffffffull); meta[1] = (u32)(incl >> 32); }
    return;
  }

  __shared__ u64 P[PCAP];         // 32 KB
  __shared__ u32 sh4[4];
  __shared__ u32 shbase;
  const int seg = blockIdx.x;
  int n = (int)segcur[seg];
  if (n > PCAP) n = PCAP;
  int np = 1; while (np < n) np <<= 1;

  for (int i=tid; i<np; i+=256)
    P[i] = (i < n) ? pairs_in[(size_t)seg*PCAP + i] : ~0ull;
  if (tid == 0) shbase = 0u;
  __syncthreads();

  // bitonic sort P[0..np)
  for (int k=2; k<=np; k<<=1){
    for (int j=k>>1; j>0; j>>=1){
      for (int i=tid; i<np; i+=256){
        const int ij = i ^ j;
        if (ij > i){
          const u64 a = P[i], b = P[ij];
          const bool up = ((i & k) == 0);
          if ((a > b) == up){ P[i] = b; P[ij] = a; }
        }
      }
      __syncthreads();
    }
  }

  // dedup + in-place left compaction (chunked; dest <= src, reads precede writes)
  for (int c=0; c<n; c+=256){
    const int i = c + tid;
    u64 key = 0ull; u32 f = 0u;
    if (i < n){
      key = P[i];
      f = (i == 0 || P[i] != P[i-1]) ? 1u : 0u;
    }
    __syncthreads();
    const u32 incl = block_scan_fast(f, sh4, tid);
    const u32 base = shbase;
    if (f) P[base + incl - 1u] = key;
    __syncthreads();
    if (tid == 255) shbase = base + incl;
    __syncthreads();
  }
  const int uc = (int)shbase;

  // write compacted unique (lo,hi) keys to global arena (overwrites pairs region)
  for (int i=tid; i<uc; i+=256) uq[(size_t)seg*PCAP + i] = P[i];

  // per-lo counts and segment-relative exclusive offsets via binary search in LDS
  const int lo0 = seg << 10;
  for (int c=0; c<1024; c+=256){
    const int lo = lo0 + c + tid;
    if (lo < NV){
      const u64 kl = (u64)(u32)lo << 32;
      const u64 kh = (u64)(u32)(lo+1) << 32;
      int a=0, b=uc;
      while (a < b){ const int m=(a+b)>>1; if (P[m] < kl) a=m+1; else b=m; }
      const int lb = a;
      b = uc;
      while (a < b){ const int m=(a+b)>>1; if (P[m] < kh) a=m+1; else b=m; }
      ucnt_ex[lo] = (u32)lb;
      ucnt[lo] = (u32)(a - lb);
    }
  }
  if (tid == 0) usum[seg] = (u32)uc;
}

// ---------------- K3: emit verts (blocks 0..195) + faces (blocks 196..3320) ----------------
__global__ void emit_all(const int* __restrict__ tet, const float* __restrict__ pos,
    const float* __restrict__ sdf, const unsigned char* __restrict__ codes,
    const u32* __restrict__ tscan, const u64* __restrict__ tsumE, const u32* __restrict__ meta,
    const u64* __restrict__ uq, const u32* __restrict__ ucnt, const u32* __restrict__ ucnt_ex,
    const u32* __restrict__ usum, float* __restrict__ out, int out_size)
{
  __shared__ u32 sh4[4];
  __shared__ u32 shu[NSEGS];
  __shared__ u32 shM;
  const int tid = threadIdx.x;
  {
    const u32 v = (tid < NSEGS) ? usum[tid] : 0u;
    const u32 incl = block_scan_fast(v, sh4, tid);
    if (tid < NSEGS) shu[tid] = incl - v;
    if (tid == NSEGS-1) shM = incl;
    __syncthreads();
  }

  if (blockIdx.x < NSEGS){
    const int seg = blockIdx.x;
    const int uc = (int)usum[seg];
    const u32 base = shu[seg];
    for (int i=tid; i<uc; i+=256){
      const u64 key = uq[(size_t)seg*PCAP + i];
      const int lo = (int)(key >> 32);
      const int hi = (int)(key & 0xffffffffull);
      const float s0 = sdf[lo], s1 = sdf[hi];
      const float d = s0 - s1;
      const float vx = (pos[3*lo  ]*(-s1) + pos[3*hi  ]*s0) / d;
      const float vy = (pos[3*lo+1]*(-s1) + pos[3*hi+1]*s0) / d;
      const float vz = (pos[3*lo+2]*(-s1) + pos[3*hi+2]*s0) / d;
      const long long w = 3ll*(long long)(base + (u32)i);
      if (w + 3 <= (long long)out_size){
        out[w] = vx; out[w+1] = vy; out[w+2] = vz;
      }
    }
  } else {
    const int t = (blockIdx.x - NSEGS)*256 + tid;   // 3125 blocks -> t < 800000 exactly
    const int code = codes[t];
    const int nt = c_ntri[code];
    if (nt == 0) return;
    const u64 tb = tsumE[t>>8];
    const u32 ts = tscan[t];
    const u32 n1e = (u32)(tb & 0xffffffffull) + (ts & 0xffffu);
    const u32 n2e = (u32)(tb >> 32) + (ts >> 16);
    const u32 N1 = meta[0];
    const u32 M  = shM;
    const u32 fb = (nt==1) ? n1e : (N1 + 2u*n2e);
    const int4 v = *(const int4*)(&tet[4*t]);
    const int vv[4] = {v.x, v.y, v.z, v.w};
    for (int r=0;r<nt;r++){
      for (int k=0;k<3;k++){
        const int e = c_tri[code][3*r+k];
        const int ia = c_be[2*e], ib = c_be[2*e+1];
        const int p = vv[ia], q = vv[ib];
        const int lo = p<q ? p : q, hi = p<q ? q : p;
        const int seg = lo >> 10;
        const u32 st = ucnt_ex[lo];
        const int u = (int)ucnt[lo];
        const u64* b = uq + (size_t)seg*PCAP + st;
        int id = -1;
        for (int j=0;j<u;j++){
          if ((int)(b[j] & 0xffffffffull) == hi){ id = (int)(shu[seg] + st) + j; break; }
        }
        const long long w = 3ll*(long long)M + 3ll*(long long)(fb + (u32)r) + k;
        if (w < (long long)out_size && id >= 0) out[w] = (float)id;
      }
    }
  }
}

// ---------------- launch: 5 dispatches ----------------
extern "C" void kernel_launch(void* const* d_in, const int* in_sizes, int n_in,
                              void* d_out, int out_size, void* d_ws, size_t ws_size,
                              hipStream_t stream)
{
  (void)in_sizes; (void)n_in; (void)ws_size;
  const float* pos = (const float*)d_in[0];
  const int*   tet = (const int*)d_in[1];
  const float* w0 = (const float*)d_in[2];
  const float* b0 = (const float*)d_in[3];
  const float* w1 = (const float*)d_in[4];
  const float* b1 = (const float*)d_in[5];
  const float* w2 = (const float*)d_in[6];
  const float* b2 = (const float*)d_in[7];
  const float* w3 = (const float*)d_in[8];
  const float* b3 = (const float*)d_in[9];
  const float* wf = (const float*)d_in[10];
  const float* bf = (const float*)d_in[11];
  float* out = (float*)d_out;
  char* ws = (char*)d_ws;

  float*         sdf   = (float*)(ws + 0);               // 800000 B
  unsigned char* codes = (unsigned char*)(ws + 800000);  // 800000 B
  u32* tscan   = (u32*)(ws + 1600000);                   // 3200000 B
  u32* tsum    = (u32*)(ws + 4800000);                   // 12800 B (3125 used)
  u64* tsumE   = (u64*)(ws + 4812800);                   // 25088 B (3125 used)
  u32* segcur  = (u32*)(ws + 4837888);                   // 1024 B (196 used)
  u32* usum    = (u32*)(ws + 4838912);                   // 1024 B
  u32* meta    = (u32*)(ws + 4839936);                   // 64 B
  u32* ucnt    = (u32*)(ws + 4840000);                   // 800000 B
  u32* ucnt_ex = (u32*)(ws + 5640000);                   // 800000 B
  _Float16* wp = (_Float16*)(ws + 6440000);              // 819200 B
  u64* pairs   = (u64*)(ws + 7259200);                   // 196*4096*8 = 6422528 B (reused as uq)
  // total ws: 13,681,728 B (< 17.6 MB proven available in prior rounds)

  split_weights<<<800,256,0,stream>>>(w0,w1,w2,w3,wp,segcur);
  mlp_mfma<<<MBLK,512,0,stream>>>(pos,wp,b0,b1,b2,b3,wf,bf,sdf);

  tet_pairs<<<NBLK,256,0,stream>>>(tet,sdf,codes,tscan,tsum,segcur,pairs);
  seg_process<<<NSEGS+1,256,0,stream>>>(pairs,segcur,pairs,ucnt,ucnt_ex,usum,tsum,tsumE,meta);
  emit_all<<<NSEGS+NBLK,256,0,stream>>>(tet,pos,sdf,codes,tscan,tsumE,meta,
                                        pairs,ucnt,ucnt_ex,usum,out,out_size);
}